// Round 1
// baseline (2022.938 us; speedup 1.0000x reference)
//
#include <hip/hip_runtime.h>
#include <math.h>

// Problem constants (verified against setup_inputs at runtime where cheap)
#define IN_DIM 128
#define HID 256
#define HEADS4 4
#define OUT_DIM 64

// ---------------------------------------------------------------------------
// CSR build (by dst). Self-loops are NOT stored; they are handled implicitly
// in the aggregation kernel (every node has exactly one).
// ---------------------------------------------------------------------------
__global__ void count_deg_kernel(const int* __restrict__ dst, int* __restrict__ deg, int e) {
    int i = blockIdx.x * blockDim.x + threadIdx.x;
    if (i < e) atomicAdd(&deg[dst[i]], 1);
}

// Single block, 1024 threads: chunked exclusive scan of deg -> offs (n+1 entries)
__global__ __launch_bounds__(1024)
void scan_offsets_kernel(const int* __restrict__ deg, int* __restrict__ offs, int n) {
    __shared__ int partial[1024];
    const int tid = threadIdx.x;
    const int chunk = (n + 1023) / 1024;
    const int lo = tid * chunk;
    const int hi = min(lo + chunk, n);
    int s = 0;
    for (int i = lo; i < hi; ++i) s += deg[i];
    partial[tid] = s;
    __syncthreads();
    // Hillis-Steele inclusive scan over 1024 partials
    for (int d = 1; d < 1024; d <<= 1) {
        int v = (tid >= d) ? partial[tid - d] : 0;
        __syncthreads();
        partial[tid] += v;
        __syncthreads();
    }
    int run = (tid == 0) ? 0 : partial[tid - 1];
    for (int i = lo; i < hi; ++i) { offs[i] = run; run += deg[i]; }
    if (hi == n) offs[n] = run;  // total (benign multi-write, same value)
}

__global__ void scatter_edges_kernel(const int* __restrict__ src, const int* __restrict__ dst,
                                     const int* __restrict__ offs, int* __restrict__ cursor,
                                     int* __restrict__ esrc, int e) {
    int i = blockIdx.x * blockDim.x + threadIdx.x;
    if (i < e) {
        int d = dst[i];
        int pos = offs[d] + atomicAdd(&cursor[d], 1);
        esrc[pos] = src[i];
    }
}

// ---------------------------------------------------------------------------
// fp32 tiled GEMM: C[M,Nc] = X[M,K] @ W[K,Nc], row-major. 64x64 tile, BK=16,
// 256 threads, 4x4 accum per thread. Xs stored transposed so both fragment
// reads are float4.
// ---------------------------------------------------------------------------
__global__ __launch_bounds__(256)
void gemm_kernel(const float* __restrict__ X, const float* __restrict__ W,
                 float* __restrict__ C, int M, int K, int Nc) {
    __shared__ float XsT[16][68];  // [k][row], pad 68 keeps float4 alignment (68*4%16==0)
    __shared__ float Ws[16][68];   // [k][col]
    const int tid = threadIdx.x;
    const int tx = tid & 15;       // col group
    const int ty = tid >> 4;       // row group
    const int brow = blockIdx.x * 64;
    const int bcol = blockIdx.y * 64;
    float acc[4][4] = {};

    for (int k0 = 0; k0 < K; k0 += 16) {
        {   // load X tile 64x16 (transposed into LDS)
            int r = tid >> 2;             // 0..63
            int c = (tid & 3) * 4;        // 0,4,8,12
            int gr = brow + r;
            float4 v = make_float4(0.f, 0.f, 0.f, 0.f);
            if (gr < M) v = *(const float4*)&X[(size_t)gr * K + k0 + c];
            XsT[c + 0][r] = v.x; XsT[c + 1][r] = v.y; XsT[c + 2][r] = v.z; XsT[c + 3][r] = v.w;
        }
        {   // load W tile 16x64
            int r = tid >> 4;             // 0..15
            int c = (tid & 15) * 4;       // 0..60
            float4 v = *(const float4*)&W[(size_t)(k0 + r) * Nc + bcol + c];
            Ws[r][c + 0] = v.x; Ws[r][c + 1] = v.y; Ws[r][c + 2] = v.z; Ws[r][c + 3] = v.w;
        }
        __syncthreads();
        #pragma unroll
        for (int kk = 0; kk < 16; ++kk) {
            const float4 a = *(const float4*)&XsT[kk][ty * 4];
            const float4 b = *(const float4*)&Ws[kk][tx * 4];
            const float av[4] = {a.x, a.y, a.z, a.w};
            const float bv[4] = {b.x, b.y, b.z, b.w};
            #pragma unroll
            for (int i = 0; i < 4; ++i)
                #pragma unroll
                for (int j = 0; j < 4; ++j)
                    acc[i][j] += av[i] * bv[j];
        }
        __syncthreads();
    }
    #pragma unroll
    for (int i = 0; i < 4; ++i) {
        int gr = brow + ty * 4 + i;
        if (gr < M) {
            float4 v = make_float4(acc[i][0], acc[i][1], acc[i][2], acc[i][3]);
            *(float4*)&C[(size_t)gr * Nc + bcol + tx * 4] = v;
        }
    }
}

// ---------------------------------------------------------------------------
// Per-(node, head) attention logits: alpha_s[n,h] = <h[n,h,:], a_src[h,:]>
// Block = HEADS*64 threads; wave w handles head w.
// ---------------------------------------------------------------------------
template <int HEADS, int CH>
__global__ void alpha_kernel(const float* __restrict__ h, const float* __restrict__ a_src,
                             const float* __restrict__ a_dst,
                             float* __restrict__ as_out, float* __restrict__ ad_out) {
    const int n = blockIdx.x;
    const int w = threadIdx.x >> 6;
    const int lane = threadIdx.x & 63;
    float ss = 0.f, sd = 0.f;
    #pragma unroll
    for (int k = 0; k < CH / 64; ++k) {
        int c = lane + k * 64;
        float v = h[(size_t)n * HEADS * CH + w * CH + c];
        ss += v * a_src[w * CH + c];
        sd += v * a_dst[w * CH + c];
    }
    #pragma unroll
    for (int o = 32; o > 0; o >>= 1) { ss += __shfl_down(ss, o); sd += __shfl_down(sd, o); }
    if (lane == 0) {
        as_out[n * HEADS + w] = ss;
        ad_out[n * HEADS + w] = sd;
    }
}

// ---------------------------------------------------------------------------
// Fused online-softmax aggregation. One block per dst node; wave w = head w.
// Single pass over incoming edges with running (max, denom, acc[CH/64]).
// Self-loop handled as the initial state. Epilogue: /denom, +bias, optional ELU.
// ---------------------------------------------------------------------------
template <int HEADS, int CH, bool ELU>
__global__ void aggregate_kernel(const float* __restrict__ h,
                                 const float* __restrict__ as_, const float* __restrict__ ad_,
                                 const int* __restrict__ offs, const int* __restrict__ esrc,
                                 const float* __restrict__ bias,
                                 float* __restrict__ out) {
    const int n = blockIdx.x;
    const int w = threadIdx.x >> 6;
    const int lane = threadIdx.x & 63;
    constexpr int PL = CH / 64;

    const float ad = ad_[n * HEADS + w];
    // self-loop: e = lrelu(as[n] + ad[n]); init m=e, denom=exp(0)=1, acc=h[n]
    float e0 = as_[n * HEADS + w] + ad;
    e0 = (e0 > 0.f) ? e0 : 0.2f * e0;
    float m = e0;
    float denom = 1.0f;
    float acc[PL];
    #pragma unroll
    for (int k = 0; k < PL; ++k)
        acc[k] = h[(size_t)n * HEADS * CH + w * CH + lane + k * 64];

    const int lo = offs[n], hi = offs[n + 1];
    for (int j = lo; j < hi; ++j) {
        const int s = esrc[j];
        float e = as_[s * HEADS + w] + ad;
        e = (e > 0.f) ? e : 0.2f * e;
        const float newm = fmaxf(m, e);
        const float corr = __expf(m - newm);
        const float p = __expf(e - newm);
        denom = denom * corr + p;
        const float* hs = &h[(size_t)s * HEADS * CH + w * CH];
        #pragma unroll
        for (int k = 0; k < PL; ++k)
            acc[k] = acc[k] * corr + p * hs[lane + k * 64];
        m = newm;
    }
    const float inv = 1.0f / (denom + 1e-16f);
    #pragma unroll
    for (int k = 0; k < PL; ++k) {
        float v = acc[k] * inv + bias[w * CH + lane + k * 64];
        if (ELU) v = (v > 0.f) ? v : (__expf(v) - 1.0f);
        out[(size_t)n * HEADS * CH + w * CH + lane + k * 64] = v;
    }
}

// ---------------------------------------------------------------------------
extern "C" void kernel_launch(void* const* d_in, const int* in_sizes, int n_in,
                              void* d_out, int out_size, void* d_ws, size_t ws_size,
                              hipStream_t stream) {
    const float* x    = (const float*)d_in[0];
    const int*   edge = (const int*)d_in[1];  // (2,E) row-major: [0..E)=src, [E..2E)=dst
    const int N = in_sizes[0] / IN_DIM;
    const int E = in_sizes[1] / 2;

    const float* W[4]; const float* As[4]; const float* Ad[4]; const float* Bb[4];
    for (int i = 0; i < 4; ++i) {
        W[i]  = (const float*)d_in[2 + 4 * i];
        As[i] = (const float*)d_in[3 + 4 * i];
        Ad[i] = (const float*)d_in[4 + 4 * i];
        Bb[i] = (const float*)d_in[5 + 4 * i];
    }

    // workspace carve-up
    char* ws = (char*)d_ws;
    auto alloc = [&](size_t bytes) {
        char* p = ws;
        ws += (bytes + 255) & ~(size_t)255;
        return p;
    };
    float* bufA   = (float*)alloc((size_t)N * 1024 * 4);  // h (GEMM out)
    float* bufB   = (float*)alloc((size_t)N * 1024 * 4);  // layer out (next x)
    float* as_buf = (float*)alloc((size_t)N * 4 * 4);
    float* ad_buf = (float*)alloc((size_t)N * 4 * 4);
    int*   deg    = (int*)alloc((size_t)(N + 1) * 4);
    int*   offs   = (int*)alloc((size_t)(N + 1) * 4);
    int*   cursor = (int*)alloc((size_t)N * 4);
    int*   esrc   = (int*)alloc((size_t)E * 4);
    (void)ws_size;

    const int* e_src = edge;
    const int* e_dst = edge + E;

    // ---- CSR build (once; shared by all 4 layers) ----
    hipMemsetAsync(deg, 0, (size_t)N * 4, stream);
    count_deg_kernel<<<(E + 255) / 256, 256, 0, stream>>>(e_dst, deg, E);
    scan_offsets_kernel<<<1, 1024, 0, stream>>>(deg, offs, N);
    hipMemsetAsync(cursor, 0, (size_t)N * 4, stream);
    scatter_edges_kernel<<<(E + 255) / 256, 256, 0, stream>>>(e_src, e_dst, offs, cursor, esrc, E);

    const dim3 blk(256);
    const dim3 gemm_grid_wide((N + 63) / 64, 1024 / 64);
    const dim3 gemm_grid_out((N + 63) / 64, OUT_DIM / 64);

    // ---- Layer 0: x(128) -> h(1024) -> B ----
    gemm_kernel<<<gemm_grid_wide, blk, 0, stream>>>(x, W[0], bufA, N, IN_DIM, 1024);
    alpha_kernel<4, 256><<<N, 256, 0, stream>>>(bufA, As[0], Ad[0], as_buf, ad_buf);
    aggregate_kernel<4, 256, true><<<N, 256, 0, stream>>>(bufA, as_buf, ad_buf, offs, esrc, Bb[0], bufB);

    // ---- Layers 1,2: B(1024) -> h(1024) -> B ----
    for (int l = 1; l <= 2; ++l) {
        gemm_kernel<<<gemm_grid_wide, blk, 0, stream>>>(bufB, W[l], bufA, N, 1024, 1024);
        alpha_kernel<4, 256><<<N, 256, 0, stream>>>(bufA, As[l], Ad[l], as_buf, ad_buf);
        aggregate_kernel<4, 256, true><<<N, 256, 0, stream>>>(bufA, as_buf, ad_buf, offs, esrc, Bb[l], bufB);
    }

    // ---- Layer 3: B(1024) -> h(64) -> d_out ----
    gemm_kernel<<<gemm_grid_out, blk, 0, stream>>>(bufB, W[3], bufA, N, 1024, OUT_DIM);
    alpha_kernel<1, 64><<<N, 64, 0, stream>>>(bufA, As[3], Ad[3], as_buf, ad_buf);
    aggregate_kernel<1, 64, false><<<N, 64, 0, stream>>>(bufA, as_buf, ad_buf, offs, esrc, Bb[3], (float*)d_out);
}

// Round 2
// 1088.189 us; speedup vs baseline: 1.8590x; 1.8590x over previous
//
#include <hip/hip_runtime.h>
#include <math.h>

#define IN_DIM 128
#define OUT_DIM 64

typedef __attribute__((ext_vector_type(8))) short bf16x8;
typedef __attribute__((ext_vector_type(4))) float f32x4;

__device__ __forceinline__ unsigned short f2bf(float f) {
    unsigned u = __float_as_uint(f);
    unsigned r = (u + 0x7FFFu + ((u >> 16) & 1u)) >> 16;   // RNE
    return (unsigned short)r;
}
__device__ __forceinline__ float bf2f(unsigned short h) {
    return __uint_as_float(((unsigned)h) << 16);
}

__device__ __forceinline__ void async_copy16(void* lds, const void* g) {
    __builtin_amdgcn_global_load_lds(
        (const __attribute__((address_space(1))) unsigned int*)g,
        (__attribute__((address_space(3))) unsigned int*)lds, 16, 0, 0);
}

// ---------------------------------------------------------------------------
// CSR build (by dst). Self-loops handled implicitly in aggregation.
// ---------------------------------------------------------------------------
__global__ void count_deg_kernel(const int* __restrict__ dst, int* __restrict__ deg, int e) {
    int i = blockIdx.x * blockDim.x + threadIdx.x;
    if (i < e) atomicAdd(&deg[dst[i]], 1);
}

__global__ __launch_bounds__(1024)
void scan_offsets_kernel(const int* __restrict__ deg, int* __restrict__ offs, int n) {
    __shared__ int partial[1024];
    const int tid = threadIdx.x;
    const int chunk = (n + 1023) / 1024;
    const int lo = tid * chunk;
    const int hi = min(lo + chunk, n);
    int s = 0;
    for (int i = lo; i < hi; ++i) s += deg[i];
    partial[tid] = s;
    __syncthreads();
    for (int d = 1; d < 1024; d <<= 1) {
        int v = (tid >= d) ? partial[tid - d] : 0;
        __syncthreads();
        partial[tid] += v;
        __syncthreads();
    }
    int run = (tid == 0) ? 0 : partial[tid - 1];
    for (int i = lo; i < hi; ++i) { offs[i] = run; run += deg[i]; }
    if (hi == n) offs[n] = run;
}

__global__ void scatter_edges_kernel(const int* __restrict__ src, const int* __restrict__ dst,
                                     const int* __restrict__ offs, int* __restrict__ cursor,
                                     int* __restrict__ esrc, int e) {
    int i = blockIdx.x * blockDim.x + threadIdx.x;
    if (i < e) {
        int d = dst[i];
        int pos = offs[d] + atomicAdd(&cursor[d], 1);
        esrc[pos] = src[i];
    }
}

// ---------------------------------------------------------------------------
// Split fp32 -> (hi, lo) bf16, element-wise (x only; layer outputs split in
// the aggregation epilogue). Rows >= M are pre-zeroed by memset.
// ---------------------------------------------------------------------------
__global__ void split_x_kernel(const float* __restrict__ x,
                               unsigned short* __restrict__ hi, unsigned short* __restrict__ lo,
                               size_t n4) {
    size_t i = (size_t)blockIdx.x * blockDim.x + threadIdx.x;
    if (i >= n4) return;
    float4 v = *(const float4*)&x[i * 4];
    ushort4 h, l;
    h.x = f2bf(v.x); l.x = f2bf(v.x - bf2f(h.x));
    h.y = f2bf(v.y); l.y = f2bf(v.y - bf2f(h.y));
    h.z = f2bf(v.z); l.z = f2bf(v.z - bf2f(h.z));
    h.w = f2bf(v.w); l.w = f2bf(v.w - bf2f(h.w));
    *(ushort4*)&hi[i * 4] = h;
    *(ushort4*)&lo[i * 4] = l;
}

// ---------------------------------------------------------------------------
// W [K][Nc] fp32 -> Wt hi/lo [Nc][K] bf16 (transposed). K, Nc multiples of 32.
// ---------------------------------------------------------------------------
__global__ __launch_bounds__(256)
void transpose_split_kernel(const float* __restrict__ W,
                            unsigned short* __restrict__ hi, unsigned short* __restrict__ lo,
                            int K, int Nc) {
    __shared__ float t[32][33];
    const int k0 = blockIdx.x * 32, n0 = blockIdx.y * 32;
    const int tx = threadIdx.x, ty = threadIdx.y;   // (32,8)
    #pragma unroll
    for (int j = 0; j < 32; j += 8)
        t[ty + j][tx] = W[(size_t)(k0 + ty + j) * Nc + n0 + tx];
    __syncthreads();
    #pragma unroll
    for (int j = 0; j < 32; j += 8) {
        float v = t[tx][ty + j];
        unsigned short h = f2bf(v);
        hi[(size_t)(n0 + ty + j) * K + k0 + tx] = h;
        lo[(size_t)(n0 + ty + j) * K + k0 + tx] = f2bf(v - bf2f(h));
    }
}

// ---------------------------------------------------------------------------
// Split-bf16 MFMA GEMM: C[Mp][Nc] (fp32, ldc) = A[Mp][K] * Wt[Npad][K]^T
// where A, Wt given as hi/lo bf16 pairs. C ~= Ahi*Bhi + Ahi*Blo + Alo*Bhi.
// 128x128 tile, BK=64, 4 waves (2x2), 16x16x32 MFMA, 4x4 frags/wave.
// global_load_lds(16B) linear LDS dest + pre-swizzled global source;
// ds_read_b128 with matching XOR swizzle (byte ^= (row&7)<<4).
// ---------------------------------------------------------------------------
__global__ __launch_bounds__(256, 2)
void gemm_split_mfma(const unsigned short* __restrict__ Ahi, const unsigned short* __restrict__ Alo,
                     const unsigned short* __restrict__ Bhi, const unsigned short* __restrict__ Blo,
                     float* __restrict__ C, int Nc, int K, int ldc) {
    __shared__ char smem[65536];          // 4 tiles x [128 rows][128 bytes]
    char* sA_hi = smem;
    char* sA_lo = smem + 16384;
    char* sB_hi = smem + 32768;
    char* sB_lo = smem + 49152;

    const int tid = threadIdx.x;
    const int w = tid >> 6;
    const int lane = tid & 63;
    const int wr = w >> 1, wc = w & 1;
    const int brow = blockIdx.x * 128;
    const int bcol = blockIdx.y * 128;

    const size_t rb = (size_t)K * 2;      // row bytes (bf16)

    // staging source pattern (per lane, 4 instrs/tile/wave)
    int rr[4], bs[4], ldso[4];
    #pragma unroll
    for (int i = 0; i < 4; ++i) {
        int d = w * 4096 + i * 1024 + lane * 16;
        ldso[i] = d;
        rr[i] = d >> 7;
        int b = d & 127;
        bs[i] = b ^ ((rr[i] & 7) << 4);
    }

    const char* gA_hi = (const char*)Ahi + (size_t)brow * rb;
    const char* gA_lo = (const char*)Alo + (size_t)brow * rb;
    const char* gB_hi = (const char*)Bhi + (size_t)bcol * rb;
    const char* gB_lo = (const char*)Blo + (size_t)bcol * rb;

    f32x4 acc[4][4];
    #pragma unroll
    for (int i = 0; i < 4; ++i)
        #pragma unroll
        for (int j = 0; j < 4; ++j) acc[i][j] = (f32x4)0.f;

    for (int k0 = 0; k0 < K; k0 += 64) {
        __syncthreads();                   // previous compute done before overwrite
        const size_t kb = (size_t)k0 * 2;
        #pragma unroll
        for (int i = 0; i < 4; ++i) {
            const size_t goff = (size_t)rr[i] * rb + kb + bs[i];
            async_copy16(sA_hi + ldso[i], gA_hi + goff);
            async_copy16(sA_lo + ldso[i], gA_lo + goff);
            async_copy16(sB_hi + ldso[i], gB_hi + goff);
            async_copy16(sB_lo + ldso[i], gB_lo + goff);
        }
        __syncthreads();                   // drains vmcnt, all tiles resident

        #pragma unroll
        for (int kk = 0; kk < 2; ++kk) {
            bf16x8 a_hi[4], a_lo[4], b_hi[4], b_lo[4];
            const int kbyte = kk * 64 + ((lane >> 4) * 16);
            #pragma unroll
            for (int f = 0; f < 4; ++f) {
                const int ra = wr * 64 + f * 16 + (lane & 15);
                const int offA = ra * 128 + (kbyte ^ ((ra & 7) << 4));
                a_hi[f] = *(const bf16x8*)(sA_hi + offA);
                a_lo[f] = *(const bf16x8*)(sA_lo + offA);
                const int rbn = wc * 64 + f * 16 + (lane & 15);
                const int offB = rbn * 128 + (kbyte ^ ((rbn & 7) << 4));
                b_hi[f] = *(const bf16x8*)(sB_hi + offB);
                b_lo[f] = *(const bf16x8*)(sB_lo + offB);
            }
            #pragma unroll
            for (int m = 0; m < 4; ++m)
                #pragma unroll
                for (int n = 0; n < 4; ++n) {
                    acc[m][n] = __builtin_amdgcn_mfma_f32_16x16x32_bf16(a_hi[m], b_hi[n], acc[m][n], 0, 0, 0);
                    acc[m][n] = __builtin_amdgcn_mfma_f32_16x16x32_bf16(a_hi[m], b_lo[n], acc[m][n], 0, 0, 0);
                    acc[m][n] = __builtin_amdgcn_mfma_f32_16x16x32_bf16(a_lo[m], b_hi[n], acc[m][n], 0, 0, 0);
                }
        }
    }

    // D layout: col = lane&15, row = (lane>>4)*4 + j   [m89-verified]
    const int rowb = brow + wr * 64 + ((lane >> 4) * 4);
    const int colb = bcol + wc * 64 + (lane & 15);
    #pragma unroll
    for (int m = 0; m < 4; ++m)
        #pragma unroll
        for (int n = 0; n < 4; ++n) {
            const int col = colb + n * 16;
            if (col < Nc) {
                #pragma unroll
                for (int j = 0; j < 4; ++j)
                    C[(size_t)(rowb + m * 16 + j) * ldc + col] = acc[m][n][j];
            }
        }
}

// ---------------------------------------------------------------------------
// Per-(node, head) attention logits.
// ---------------------------------------------------------------------------
template <int HEADS, int CH>
__global__ void alpha_kernel(const float* __restrict__ h, const float* __restrict__ a_src,
                             const float* __restrict__ a_dst,
                             float* __restrict__ as_out, float* __restrict__ ad_out) {
    const int n = blockIdx.x;
    const int w = threadIdx.x >> 6;
    const int lane = threadIdx.x & 63;
    float ss = 0.f, sd = 0.f;
    #pragma unroll
    for (int k = 0; k < CH / 64; ++k) {
        int c = lane + k * 64;
        float v = h[(size_t)n * HEADS * CH + w * CH + c];
        ss += v * a_src[w * CH + c];
        sd += v * a_dst[w * CH + c];
    }
    #pragma unroll
    for (int o = 32; o > 0; o >>= 1) { ss += __shfl_down(ss, o); sd += __shfl_down(sd, o); }
    if (lane == 0) {
        as_out[n * HEADS + w] = ss;
        ad_out[n * HEADS + w] = sd;
    }
}

// ---------------------------------------------------------------------------
// Fused online-softmax aggregation; epilogue writes either fp32 (final layer)
// or split hi/lo bf16 (feeds next layer's GEMM A operand directly).
// ---------------------------------------------------------------------------
template <int HEADS, int CH, bool ELU, bool SPLIT>
__global__ void aggregate_kernel(const float* __restrict__ h,
                                 const float* __restrict__ as_, const float* __restrict__ ad_,
                                 const int* __restrict__ offs, const int* __restrict__ esrc,
                                 const float* __restrict__ bias,
                                 float* __restrict__ out_f32,
                                 unsigned short* __restrict__ out_hi,
                                 unsigned short* __restrict__ out_lo) {
    const int n = blockIdx.x;
    const int w = threadIdx.x >> 6;
    const int lane = threadIdx.x & 63;
    constexpr int PL = CH / 64;

    const float ad = ad_[n * HEADS + w];
    float e0 = as_[n * HEADS + w] + ad;
    e0 = (e0 > 0.f) ? e0 : 0.2f * e0;
    float m = e0;
    float denom = 1.0f;
    float acc[PL];
    #pragma unroll
    for (int k = 0; k < PL; ++k)
        acc[k] = h[(size_t)n * HEADS * CH + w * CH + lane + k * 64];

    const int lo = offs[n], hi = offs[n + 1];
    for (int j = lo; j < hi; ++j) {
        const int s = esrc[j];
        float e = as_[s * HEADS + w] + ad;
        e = (e > 0.f) ? e : 0.2f * e;
        const float newm = fmaxf(m, e);
        const float corr = __expf(m - newm);
        const float p = __expf(e - newm);
        denom = denom * corr + p;
        const float* hs = &h[(size_t)s * HEADS * CH + w * CH];
        #pragma unroll
        for (int k = 0; k < PL; ++k)
            acc[k] = acc[k] * corr + p * hs[lane + k * 64];
        m = newm;
    }
    const float inv = 1.0f / (denom + 1e-16f);
    #pragma unroll
    for (int k = 0; k < PL; ++k) {
        float v = acc[k] * inv + bias[w * CH + lane + k * 64];
        if (ELU) v = (v > 0.f) ? v : (__expf(v) - 1.0f);
        const size_t o = (size_t)n * HEADS * CH + w * CH + lane + k * 64;
        if (SPLIT) {
            unsigned short hb = f2bf(v);
            out_hi[o] = hb;
            out_lo[o] = f2bf(v - bf2f(hb));
        } else {
            out_f32[o] = v;
        }
    }
}

// ---------------------------------------------------------------------------
extern "C" void kernel_launch(void* const* d_in, const int* in_sizes, int n_in,
                              void* d_out, int out_size, void* d_ws, size_t ws_size,
                              hipStream_t stream) {
    const float* x    = (const float*)d_in[0];
    const int*   edge = (const int*)d_in[1];
    const int N = in_sizes[0] / IN_DIM;
    const int E = in_sizes[1] / 2;
    const int Mp = ((N + 127) / 128) * 128;     // padded rows

    const float* W[4]; const float* As[4]; const float* Ad[4]; const float* Bb[4];
    for (int i = 0; i < 4; ++i) {
        W[i]  = (const float*)d_in[2 + 4 * i];
        As[i] = (const float*)d_in[3 + 4 * i];
        Ad[i] = (const float*)d_in[4 + 4 * i];
        Bb[i] = (const float*)d_in[5 + 4 * i];
    }

    char* ws = (char*)d_ws;
    auto alloc = [&](size_t bytes) {
        char* p = ws;
        ws += (bytes + 255) & ~(size_t)255;
        return p;
    };
    float*          bufA  = (float*)alloc((size_t)Mp * 1024 * 4);          // GEMM out h (fp32)
    unsigned short* Xhi   = (unsigned short*)alloc((size_t)Mp * 1024 * 2); // layer input hi
    unsigned short* Xlo   = (unsigned short*)alloc((size_t)Mp * 1024 * 2); // layer input lo
    unsigned short* Wthi  = (unsigned short*)alloc((size_t)1024 * 1024 * 2);
    unsigned short* Wtlo  = (unsigned short*)alloc((size_t)1024 * 1024 * 2);
    float*          as_buf = (float*)alloc((size_t)N * 4 * 4);
    float*          ad_buf = (float*)alloc((size_t)N * 4 * 4);
    int*            deg    = (int*)alloc((size_t)(N + 1) * 4);
    int*            offs   = (int*)alloc((size_t)(N + 1) * 4);
    int*            cursor = (int*)alloc((size_t)N * 4);
    int*            esrc   = (int*)alloc((size_t)E * 4);
    (void)ws_size;

    const int* e_src = edge;
    const int* e_dst = edge + E;

    // ---- CSR build ----
    hipMemsetAsync(deg, 0, (size_t)N * 4, stream);
    count_deg_kernel<<<(E + 255) / 256, 256, 0, stream>>>(e_dst, deg, E);
    scan_offsets_kernel<<<1, 1024, 0, stream>>>(deg, offs, N);
    hipMemsetAsync(cursor, 0, (size_t)N * 4, stream);
    scatter_edges_kernel<<<(E + 255) / 256, 256, 0, stream>>>(e_src, e_dst, offs, cursor, esrc, E);

    // ---- zero split buffers (pad rows must read as 0 in GEMM) ----
    hipMemsetAsync(Xhi, 0, (size_t)Mp * 1024 * 2, stream);
    hipMemsetAsync(Xlo, 0, (size_t)Mp * 1024 * 2, stream);

    // ---- layer 0 input split: x [N][128] ----
    {
        size_t n4 = (size_t)N * IN_DIM / 4;
        split_x_kernel<<<(unsigned)((n4 + 255) / 256), 256, 0, stream>>>(x, Xhi, Xlo, n4);
    }

    const dim3 tblk(32, 8);
    const int gx = Mp / 128;

    // ---- Layer 0: K=128 -> h(1024) ----
    transpose_split_kernel<<<dim3(IN_DIM / 32, 1024 / 32), tblk, 0, stream>>>(W[0], Wthi, Wtlo, IN_DIM, 1024);
    gemm_split_mfma<<<dim3(gx, 8), 256, 0, stream>>>(Xhi, Xlo, Wthi, Wtlo, bufA, 1024, IN_DIM, 1024);
    alpha_kernel<4, 256><<<N, 256, 0, stream>>>(bufA, As[0], Ad[0], as_buf, ad_buf);
    aggregate_kernel<4, 256, true, true><<<N, 256, 0, stream>>>(bufA, as_buf, ad_buf, offs, esrc, Bb[0], nullptr, Xhi, Xlo);

    // ---- Layers 1,2: K=1024 -> h(1024) ----
    for (int l = 1; l <= 2; ++l) {
        transpose_split_kernel<<<dim3(1024 / 32, 1024 / 32), tblk, 0, stream>>>(W[l], Wthi, Wtlo, 1024, 1024);
        gemm_split_mfma<<<dim3(gx, 8), 256, 0, stream>>>(Xhi, Xlo, Wthi, Wtlo, bufA, 1024, 1024, 1024);
        alpha_kernel<4, 256><<<N, 256, 0, stream>>>(bufA, As[l], Ad[l], as_buf, ad_buf);
        aggregate_kernel<4, 256, true, true><<<N, 256, 0, stream>>>(bufA, as_buf, ad_buf, offs, esrc, Bb[l], nullptr, Xhi, Xlo);
    }

    // ---- Layer 3: K=1024 -> h(64), mean over 1 head, fp32 out ----
    hipMemsetAsync(Wthi, 0, (size_t)128 * 1024 * 2, stream);   // pad cols 64..127
    hipMemsetAsync(Wtlo, 0, (size_t)128 * 1024 * 2, stream);
    transpose_split_kernel<<<dim3(1024 / 32, OUT_DIM / 32), tblk, 0, stream>>>(W[3], Wthi, Wtlo, 1024, OUT_DIM);
    gemm_split_mfma<<<dim3(gx, 1), 256, 0, stream>>>(Xhi, Xlo, Wthi, Wtlo, bufA, OUT_DIM, 1024, OUT_DIM);
    alpha_kernel<1, 64><<<N, 64, 0, stream>>>(bufA, As[3], Ad[3], as_buf, ad_buf);
    aggregate_kernel<1, 64, false, false><<<N, 64, 0, stream>>>(bufA, as_buf, ad_buf, offs, esrc, Bb[3], (float*)d_out, nullptr, nullptr);
}

// Round 3
// 1009.362 us; speedup vs baseline: 2.0042x; 1.0781x over previous
//
#include <hip/hip_runtime.h>
#include <math.h>

#define IN_DIM 128
#define OUT_DIM 64

typedef __attribute__((ext_vector_type(8))) short bf16x8;
typedef __attribute__((ext_vector_type(4))) float f32x4;

__device__ __forceinline__ unsigned short f2bf(float f) {
    unsigned u = __float_as_uint(f);
    unsigned r = (u + 0x7FFFu + ((u >> 16) & 1u)) >> 16;   // RNE
    return (unsigned short)r;
}
__device__ __forceinline__ float bf2f(unsigned short h) {
    return __uint_as_float(((unsigned)h) << 16);
}

__device__ __forceinline__ void async_copy16(void* lds, const void* g) {
    __builtin_amdgcn_global_load_lds(
        (const __attribute__((address_space(1))) unsigned int*)g,
        (__attribute__((address_space(3))) unsigned int*)lds, 16, 0, 0);
}

// ---------------------------------------------------------------------------
// CSR build (by dst). Self-loops handled implicitly in aggregation.
// ---------------------------------------------------------------------------
__global__ void count_deg_kernel(const int* __restrict__ dst, int* __restrict__ deg, int e) {
    int i = blockIdx.x * blockDim.x + threadIdx.x;
    if (i < e) atomicAdd(&deg[dst[i]], 1);
}

__global__ __launch_bounds__(1024)
void scan_offsets_kernel(const int* __restrict__ deg, int* __restrict__ offs, int n) {
    __shared__ int partial[1024];
    const int tid = threadIdx.x;
    const int chunk = (n + 1023) / 1024;
    const int lo = tid * chunk;
    const int hi = min(lo + chunk, n);
    int s = 0;
    for (int i = lo; i < hi; ++i) s += deg[i];
    partial[tid] = s;
    __syncthreads();
    for (int d = 1; d < 1024; d <<= 1) {
        int v = (tid >= d) ? partial[tid - d] : 0;
        __syncthreads();
        partial[tid] += v;
        __syncthreads();
    }
    int run = (tid == 0) ? 0 : partial[tid - 1];
    for (int i = lo; i < hi; ++i) { offs[i] = run; run += deg[i]; }
    if (hi == n) offs[n] = run;
}

__global__ void scatter_edges_kernel(const int* __restrict__ src, const int* __restrict__ dst,
                                     const int* __restrict__ offs, int* __restrict__ cursor,
                                     int* __restrict__ esrc, int e) {
    int i = blockIdx.x * blockDim.x + threadIdx.x;
    if (i < e) {
        int d = dst[i];
        int pos = offs[d] + atomicAdd(&cursor[d], 1);
        esrc[pos] = src[i];
    }
}

// ---------------------------------------------------------------------------
// Split fp32 -> (hi, lo) bf16 for the layer-0 input x.
// ---------------------------------------------------------------------------
__global__ void split_x_kernel(const float* __restrict__ x,
                               unsigned short* __restrict__ hi, unsigned short* __restrict__ lo,
                               size_t n4) {
    size_t i = (size_t)blockIdx.x * blockDim.x + threadIdx.x;
    if (i >= n4) return;
    float4 v = *(const float4*)&x[i * 4];
    ushort4 h, l;
    h.x = f2bf(v.x); l.x = f2bf(v.x - bf2f(h.x));
    h.y = f2bf(v.y); l.y = f2bf(v.y - bf2f(h.y));
    h.z = f2bf(v.z); l.z = f2bf(v.z - bf2f(h.z));
    h.w = f2bf(v.w); l.w = f2bf(v.w - bf2f(h.w));
    *(ushort4*)&hi[i * 4] = h;
    *(ushort4*)&lo[i * 4] = l;
}

// ---------------------------------------------------------------------------
// W [K][Nc] fp32 -> Wt hi/lo [Nc][K] bf16 (transposed).
// ---------------------------------------------------------------------------
__global__ __launch_bounds__(256)
void transpose_split_kernel(const float* __restrict__ W,
                            unsigned short* __restrict__ hi, unsigned short* __restrict__ lo,
                            int K, int Nc) {
    __shared__ float t[32][33];
    const int k0 = blockIdx.x * 32, n0 = blockIdx.y * 32;
    const int tx = threadIdx.x, ty = threadIdx.y;   // (32,8)
    #pragma unroll
    for (int j = 0; j < 32; j += 8)
        t[ty + j][tx] = W[(size_t)(k0 + ty + j) * Nc + n0 + tx];
    __syncthreads();
    #pragma unroll
    for (int j = 0; j < 32; j += 8) {
        float v = t[tx][ty + j];
        unsigned short h = f2bf(v);
        hi[(size_t)(n0 + ty + j) * K + k0 + tx] = h;
        lo[(size_t)(n0 + ty + j) * K + k0 + tx] = f2bf(v - bf2f(h));
    }
}

// ---------------------------------------------------------------------------
// Split-bf16 MFMA GEMM, 128x128 tile, BK=64, 4 waves, 16x16x32 MFMA.
// C written HEAD-MAJOR: addr = (col>>8)*hstride + row*cph + (col&255).
//   layers 0-2: cph=256, hstride=Mp*256  ->  h[head][Mp][256]
//   layer  3 : cph=64  (col<64 -> head 0) ->  h[row][64]
// ---------------------------------------------------------------------------
__global__ __launch_bounds__(256, 2)
void gemm_split_mfma(const unsigned short* __restrict__ Ahi, const unsigned short* __restrict__ Alo,
                     const unsigned short* __restrict__ Bhi, const unsigned short* __restrict__ Blo,
                     float* __restrict__ C, int Nc, int K, int cph, size_t hstride) {
    __shared__ char smem[65536];
    char* sA_hi = smem;
    char* sA_lo = smem + 16384;
    char* sB_hi = smem + 32768;
    char* sB_lo = smem + 49152;

    const int tid = threadIdx.x;
    const int w = tid >> 6;
    const int lane = tid & 63;
    const int wr = w >> 1, wc = w & 1;
    const int brow = blockIdx.x * 128;
    const int bcol = blockIdx.y * 128;

    const size_t rb = (size_t)K * 2;

    int rr[4], bs[4], ldso[4];
    #pragma unroll
    for (int i = 0; i < 4; ++i) {
        int d = w * 4096 + i * 1024 + lane * 16;
        ldso[i] = d;
        rr[i] = d >> 7;
        int b = d & 127;
        bs[i] = b ^ ((rr[i] & 7) << 4);
    }

    const char* gA_hi = (const char*)Ahi + (size_t)brow * rb;
    const char* gA_lo = (const char*)Alo + (size_t)brow * rb;
    const char* gB_hi = (const char*)Bhi + (size_t)bcol * rb;
    const char* gB_lo = (const char*)Blo + (size_t)bcol * rb;

    f32x4 acc[4][4];
    #pragma unroll
    for (int i = 0; i < 4; ++i)
        #pragma unroll
        for (int j = 0; j < 4; ++j) acc[i][j] = (f32x4)0.f;

    for (int k0 = 0; k0 < K; k0 += 64) {
        __syncthreads();
        const size_t kb = (size_t)k0 * 2;
        #pragma unroll
        for (int i = 0; i < 4; ++i) {
            const size_t goff = (size_t)rr[i] * rb + kb + bs[i];
            async_copy16(sA_hi + ldso[i], gA_hi + goff);
            async_copy16(sA_lo + ldso[i], gA_lo + goff);
            async_copy16(sB_hi + ldso[i], gB_hi + goff);
            async_copy16(sB_lo + ldso[i], gB_lo + goff);
        }
        __syncthreads();

        #pragma unroll
        for (int kk = 0; kk < 2; ++kk) {
            bf16x8 a_hi[4], a_lo[4], b_hi[4], b_lo[4];
            const int kbyte = kk * 64 + ((lane >> 4) * 16);
            #pragma unroll
            for (int f = 0; f < 4; ++f) {
                const int ra = wr * 64 + f * 16 + (lane & 15);
                const int offA = ra * 128 + (kbyte ^ ((ra & 7) << 4));
                a_hi[f] = *(const bf16x8*)(sA_hi + offA);
                a_lo[f] = *(const bf16x8*)(sA_lo + offA);
                const int rbn = wc * 64 + f * 16 + (lane & 15);
                const int offB = rbn * 128 + (kbyte ^ ((rbn & 7) << 4));
                b_hi[f] = *(const bf16x8*)(sB_hi + offB);
                b_lo[f] = *(const bf16x8*)(sB_lo + offB);
            }
            #pragma unroll
            for (int m = 0; m < 4; ++m)
                #pragma unroll
                for (int n = 0; n < 4; ++n) {
                    acc[m][n] = __builtin_amdgcn_mfma_f32_16x16x32_bf16(a_hi[m], b_hi[n], acc[m][n], 0, 0, 0);
                    acc[m][n] = __builtin_amdgcn_mfma_f32_16x16x32_bf16(a_hi[m], b_lo[n], acc[m][n], 0, 0, 0);
                    acc[m][n] = __builtin_amdgcn_mfma_f32_16x16x32_bf16(a_lo[m], b_hi[n], acc[m][n], 0, 0, 0);
                }
        }
    }

    const int rowb = brow + wr * 64 + ((lane >> 4) * 4);
    const int colb = bcol + wc * 64 + (lane & 15);
    #pragma unroll
    for (int m = 0; m < 4; ++m)
        #pragma unroll
        for (int n = 0; n < 4; ++n) {
            const int col = colb + n * 16;
            if (col < Nc) {
                const size_t base = (size_t)(col >> 8) * hstride + (size_t)(col & 255);
                #pragma unroll
                for (int j = 0; j < 4; ++j)
                    C[base + (size_t)(rowb + m * 16 + j) * cph] = acc[m][n][j];
            }
        }
}

// ---------------------------------------------------------------------------
// Attention logits. h head-major [HEADS][hm][CH]; outputs head-major [HEADS][N].
// ---------------------------------------------------------------------------
template <int HEADS, int CH>
__global__ void alpha_kernel(const float* __restrict__ h, const float* __restrict__ a_src,
                             const float* __restrict__ a_dst,
                             float* __restrict__ as_out, float* __restrict__ ad_out,
                             int N, int hm) {
    const int n = blockIdx.x;
    const int w = threadIdx.x >> 6;
    const int lane = threadIdx.x & 63;
    float ss = 0.f, sd = 0.f;
    #pragma unroll
    for (int k = 0; k < CH / 64; ++k) {
        int c = lane + k * 64;
        float v = h[((size_t)w * hm + n) * CH + c];
        ss += v * a_src[w * CH + c];
        sd += v * a_dst[w * CH + c];
    }
    #pragma unroll
    for (int o = 32; o > 0; o >>= 1) { ss += __shfl_down(ss, o); sd += __shfl_down(sd, o); }
    if (lane == 0) {
        as_out[(size_t)w * N + n] = ss;
        ad_out[(size_t)w * N + n] = sd;
    }
}

// ---------------------------------------------------------------------------
// Fused online-softmax aggregation, head-phased: grid (N, HEADS), 64 threads.
// blockIdx.y = head -> dispatch processes one head at a time, so the gathered
// h slice (hm*CH*4 bytes) stays L2/L3-hot. float4 gather (CH=256).
// ---------------------------------------------------------------------------
template <int CH, bool ELU, bool SPLIT>
__global__ __launch_bounds__(64)
void aggregate_kernel(const float* __restrict__ h,      // [heads][hm][CH]
                      const float* __restrict__ as_,    // [heads][N]
                      const float* __restrict__ ad_,
                      const int* __restrict__ offs, const int* __restrict__ esrc,
                      const float* __restrict__ bias,   // [heads*CH]
                      int N, int hm, int ldo,
                      float* __restrict__ out_f32,
                      unsigned short* __restrict__ out_hi,
                      unsigned short* __restrict__ out_lo) {
    const int n = blockIdx.x;
    const int w = blockIdx.y;
    const int lane = threadIdx.x;
    constexpr int V = CH / 64;  // 4 (big layers) or 1 (layer 3)

    const float* hw = h + (size_t)w * hm * CH;
    const float* asw = as_ + (size_t)w * N;

    const float ad = ad_[(size_t)w * N + n];
    float e0 = asw[n] + ad;
    e0 = (e0 > 0.f) ? e0 : 0.2f * e0;
    float m = e0;
    float denom = 1.0f;

    float acc[V];
    {
        const float* hn = hw + (size_t)n * CH + lane * V;
        if (V == 4) {
            float4 t = *(const float4*)hn;
            acc[0] = t.x; acc[1] = t.y; acc[2] = t.z; acc[3] = t.w;
        } else {
            acc[0] = *hn;
        }
    }

    const int lo = offs[n], hi = offs[n + 1];
    for (int j = lo; j < hi; ++j) {
        const int s = esrc[j];
        float e = asw[s] + ad;
        e = (e > 0.f) ? e : 0.2f * e;
        const float newm = fmaxf(m, e);
        const float corr = __expf(m - newm);
        const float p = __expf(e - newm);
        denom = denom * corr + p;
        const float* hs = hw + (size_t)s * CH + lane * V;
        if (V == 4) {
            float4 t = *(const float4*)hs;
            acc[0] = acc[0] * corr + p * t.x;
            acc[1] = acc[1] * corr + p * t.y;
            acc[2] = acc[2] * corr + p * t.z;
            acc[3] = acc[3] * corr + p * t.w;
        } else {
            acc[0] = acc[0] * corr + p * hs[0];
        }
        m = newm;
    }

    const float inv = 1.0f / (denom + 1e-16f);
    float v[V];
    #pragma unroll
    for (int k = 0; k < V; ++k) {
        v[k] = acc[k] * inv + bias[w * CH + lane * V + k];
        if (ELU) v[k] = (v[k] > 0.f) ? v[k] : (__expf(v[k]) - 1.0f);
    }
    const size_t o = (size_t)n * ldo + (size_t)w * CH + lane * V;
    if (SPLIT) {
        if (V == 4) {
            ushort4 hv, lv;
            hv.x = f2bf(v[0]); lv.x = f2bf(v[0] - bf2f(hv.x));
            hv.y = f2bf(v[1]); lv.y = f2bf(v[1] - bf2f(hv.y));
            hv.z = f2bf(v[2]); lv.z = f2bf(v[2] - bf2f(hv.z));
            hv.w = f2bf(v[3]); lv.w = f2bf(v[3] - bf2f(hv.w));
            *(ushort4*)&out_hi[o] = hv;
            *(ushort4*)&out_lo[o] = lv;
        } else {
            unsigned short hb = f2bf(v[0]);
            out_hi[o] = hb;
            out_lo[o] = f2bf(v[0] - bf2f(hb));
        }
    } else {
        #pragma unroll
        for (int k = 0; k < V; ++k) out_f32[o + k] = v[k];
    }
}

// ---------------------------------------------------------------------------
extern "C" void kernel_launch(void* const* d_in, const int* in_sizes, int n_in,
                              void* d_out, int out_size, void* d_ws, size_t ws_size,
                              hipStream_t stream) {
    const float* x    = (const float*)d_in[0];
    const int*   edge = (const int*)d_in[1];
    const int N = in_sizes[0] / IN_DIM;
    const int E = in_sizes[1] / 2;
    const int Mp = ((N + 127) / 128) * 128;

    const float* W[4]; const float* As[4]; const float* Ad[4]; const float* Bb[4];
    for (int i = 0; i < 4; ++i) {
        W[i]  = (const float*)d_in[2 + 4 * i];
        As[i] = (const float*)d_in[3 + 4 * i];
        Ad[i] = (const float*)d_in[4 + 4 * i];
        Bb[i] = (const float*)d_in[5 + 4 * i];
    }

    char* ws = (char*)d_ws;
    auto alloc = [&](size_t bytes) {
        char* p = ws;
        ws += (bytes + 255) & ~(size_t)255;
        return p;
    };
    float*          bufA  = (float*)alloc((size_t)Mp * 1024 * 4);          // h, head-major [4][Mp][256]
    unsigned short* Xhi   = (unsigned short*)alloc((size_t)Mp * 1024 * 2);
    unsigned short* Xlo   = (unsigned short*)alloc((size_t)Mp * 1024 * 2);
    unsigned short* Wthi  = (unsigned short*)alloc((size_t)1024 * 1024 * 2);
    unsigned short* Wtlo  = (unsigned short*)alloc((size_t)1024 * 1024 * 2);
    float*          as_buf = (float*)alloc((size_t)N * 4 * 4);
    float*          ad_buf = (float*)alloc((size_t)N * 4 * 4);
    int*            deg    = (int*)alloc((size_t)(N + 1) * 4);
    int*            offs   = (int*)alloc((size_t)(N + 1) * 4);
    int*            cursor = (int*)alloc((size_t)N * 4);
    int*            esrc   = (int*)alloc((size_t)E * 4);
    (void)ws_size;

    const int* e_src = edge;
    const int* e_dst = edge + E;

    // ---- CSR build ----
    hipMemsetAsync(deg, 0, (size_t)N * 4, stream);
    count_deg_kernel<<<(E + 255) / 256, 256, 0, stream>>>(e_dst, deg, E);
    scan_offsets_kernel<<<1, 1024, 0, stream>>>(deg, offs, N);
    hipMemsetAsync(cursor, 0, (size_t)N * 4, stream);
    scatter_edges_kernel<<<(E + 255) / 256, 256, 0, stream>>>(e_src, e_dst, offs, cursor, esrc, E);

    // ---- zero only the pad rows of the split A views ----
    // layer-0 view [Mp][128]: pad bytes [N*256, Mp*256)
    hipMemsetAsync((char*)Xhi + (size_t)N * 256, 0, (size_t)(Mp - N) * 256, stream);
    hipMemsetAsync((char*)Xlo + (size_t)N * 256, 0, (size_t)(Mp - N) * 256, stream);
    // layers 1-3 view [Mp][1024]: pad bytes [N*2048, Mp*2048)
    hipMemsetAsync((char*)Xhi + (size_t)N * 2048, 0, (size_t)(Mp - N) * 2048, stream);
    hipMemsetAsync((char*)Xlo + (size_t)N * 2048, 0, (size_t)(Mp - N) * 2048, stream);

    // ---- layer 0 input split ----
    {
        size_t n4 = (size_t)N * IN_DIM / 4;
        split_x_kernel<<<(unsigned)((n4 + 255) / 256), 256, 0, stream>>>(x, Xhi, Xlo, n4);
    }

    const dim3 tblk(32, 8);
    const int gx = Mp / 128;
    const size_t hstride = (size_t)Mp * 256;

    // ---- Layer 0 ----
    transpose_split_kernel<<<dim3(IN_DIM / 32, 1024 / 32), tblk, 0, stream>>>(W[0], Wthi, Wtlo, IN_DIM, 1024);
    gemm_split_mfma<<<dim3(gx, 8), 256, 0, stream>>>(Xhi, Xlo, Wthi, Wtlo, bufA, 1024, IN_DIM, 256, hstride);
    alpha_kernel<4, 256><<<N, 256, 0, stream>>>(bufA, As[0], Ad[0], as_buf, ad_buf, N, Mp);
    aggregate_kernel<256, true, true><<<dim3(N, 4), 64, 0, stream>>>(
        bufA, as_buf, ad_buf, offs, esrc, Bb[0], N, Mp, 1024, nullptr, Xhi, Xlo);

    // ---- Layers 1,2 ----
    for (int l = 1; l <= 2; ++l) {
        transpose_split_kernel<<<dim3(1024 / 32, 1024 / 32), tblk, 0, stream>>>(W[l], Wthi, Wtlo, 1024, 1024);
        gemm_split_mfma<<<dim3(gx, 8), 256, 0, stream>>>(Xhi, Xlo, Wthi, Wtlo, bufA, 1024, 1024, 256, hstride);
        alpha_kernel<4, 256><<<N, 256, 0, stream>>>(bufA, As[l], Ad[l], as_buf, ad_buf, N, Mp);
        aggregate_kernel<256, true, true><<<dim3(N, 4), 64, 0, stream>>>(
            bufA, as_buf, ad_buf, offs, esrc, Bb[l], N, Mp, 1024, nullptr, Xhi, Xlo);
    }

    // ---- Layer 3: K=1024 -> h(64), 1 head, fp32 out ----
    hipMemsetAsync(Wthi, 0, (size_t)128 * 1024 * 2, stream);
    hipMemsetAsync(Wtlo, 0, (size_t)128 * 1024 * 2, stream);
    transpose_split_kernel<<<dim3(1024 / 32, OUT_DIM / 32), tblk, 0, stream>>>(W[3], Wthi, Wtlo, 1024, OUT_DIM);
    gemm_split_mfma<<<dim3(gx, 1), 256, 0, stream>>>(Xhi, Xlo, Wthi, Wtlo, bufA, OUT_DIM, 1024, OUT_DIM, 0);
    alpha_kernel<1, 64><<<N, 64, 0, stream>>>(bufA, As[3], Ad[3], as_buf, ad_buf, N, Mp);
    aggregate_kernel<64, false, false><<<dim3(N, 1), 64, 0, stream>>>(
        bufA, as_buf, ad_buf, offs, esrc, Bb[3], N, Mp, OUT_DIM, (float*)d_out, nullptr, nullptr);
}